// Round 5
// baseline (2110.034 us; speedup 1.0000x reference)
//
#include <hip/hip_runtime.h>

// LSTMClassifier: B=4096, T=128, I=32, H=64, 2-layer LSTM + MLP head.
// Round 5: producer/consumer BLOCK split. 512 blocks x 256 threads; pair
// p = blockIdx/2 owns batch rows [16p,16p+16). Even block = layer-0 producer
// (4 waves, own barrier), odd block = layer-1 consumer (4 waves, own barrier).
// h0 handoff via 16-slot ring in d_ws with agent-scope atomics (flag[s]==s+1
// exact-match => 0xAA poison immune; signed progress counter => poison-safe
// backpressure). Consumer skew 3 steps + 1-iter prefetch hides IF$ latency.
// Two blocks/CU => each SIMD hosts one P-wave + one C-wave with INDEPENDENT
// barriers -> phase-decorrelated MFMA/trans issue (the round-3 stall fix).
// f16 MFMA operands, fp32 state; 7 transcendentals/cell (combined rcp).

#define TT 128
#define RING 16
#define SLOT_DW 512                       // 16 rows x 64 units f16 = 512 dwords
#define FLAGS_OFF (RING * SLOT_DW)        // dword offsets within a pair
#define PROG_OFF  (FLAGS_OFF + 192)
#define PAIR_DW   (FLAGS_OFF + 256)       // 33792 B/pair * 256 pairs = 8.7 MB

typedef _Float16 half8 __attribute__((ext_vector_type(8)));
typedef float floatx4 __attribute__((ext_vector_type(4)));
typedef unsigned int uint;

#define LOG2E 1.4426950408889634f

__device__ __forceinline__ void ws_store(uint* p, uint v) {
    __hip_atomic_store(p, v, __ATOMIC_RELAXED, __HIP_MEMORY_SCOPE_AGENT);
}
__device__ __forceinline__ uint ws_load(const uint* p) {
    return __hip_atomic_load(p, __ATOMIC_RELAXED, __HIP_MEMORY_SCOPE_AGENT);
}

// Load 8 consecutive fp32 of row n (K-major) and convert to an f16 MFMA fragment.
__device__ __forceinline__ half8 load_w_frag(const float* __restrict__ W, int n, int K, int k0) {
    const float* p = W + (size_t)n * K + k0;
    float4 a = *(const float4*)p;
    float4 b = *(const float4*)(p + 4);
    half8 h;
    h[0] = (_Float16)a.x; h[1] = (_Float16)a.y; h[2] = (_Float16)a.z; h[3] = (_Float16)a.w;
    h[4] = (_Float16)b.x; h[5] = (_Float16)b.y; h[6] = (_Float16)b.z; h[7] = (_Float16)b.w;
    return h;
}

// LSTM cell eltwise, 7 transcendentals (5 exp + 2 rcp):
// sig(f) and sig(i)*tanh(g) share one rcp via R = rcp(D1*D2);
// clamps at +-12 keep D1*D2 <= ~7e20 (fp32-safe) with tail error < 7e-6.
__device__ __forceinline__ void cell_update(float gi, float gf, float gg, float go,
                                            float& c, float& h) {
    gi = fminf(fmaxf(gi, -12.f), 12.f);
    gf = fminf(fmaxf(gf, -12.f), 12.f);
    gg = fminf(fmaxf(gg, -12.f), 12.f);
    float u  = __builtin_amdgcn_exp2f(gg * (2.f * LOG2E));   // e^{2g} <= 2.7e10
    float vi = __builtin_amdgcn_exp2f(-gi * LOG2E);          // <= 1.6e5
    float vf = __builtin_amdgcn_exp2f(-gf * LOG2E);          // <= 1.6e5
    float u1 = u + 1.f;
    float D1 = 1.f + vf;
    float D2 = fmaf(vi, u1, u1);                             // (1+vi)(1+u)
    float R  = __builtin_amdgcn_rcpf(D1 * D2);
    float sigf = R * D2;                                     // = 1/D1
    float sit  = (u - 1.f) * (R * D1);                       // = (u-1)/D2
    c = fmaf(sigf, c, sit);
    float cc = fminf(fmaxf(c, -12.f), 12.f);
    float w  = __builtin_amdgcn_exp2f(cc * (2.f * LOG2E));
    float vo = __builtin_amdgcn_exp2f(-go * LOG2E);
    float w1 = w + 1.f;
    float den = fmaf(vo, w1, w1);                            // (1+vo)(w+1) <= 2.6e23
    h = (w - 1.f) * __builtin_amdgcn_rcpf(den);
}

__global__ __launch_bounds__(256, 2) void lstm_pc(
    const float* __restrict__ x,
    const float* __restrict__ Wih0, const float* __restrict__ Whh0,
    const float* __restrict__ bih0, const float* __restrict__ bhh0,
    const float* __restrict__ Wih1, const float* __restrict__ Whh1,
    const float* __restrict__ bih1, const float* __restrict__ bhh1,
    const float* __restrict__ Wc1, const float* __restrict__ bc1,
    const float* __restrict__ Wc2, const float* __restrict__ bc2,
    float* __restrict__ out, uint* __restrict__ ws)
{
    // +8 f16 pad: 16B-aligned rows (144B stride), 2-way bank alias only (free).
    __shared__ __align__(16) _Float16 xs[2][16][40];    // producer only
    __shared__ __align__(16) _Float16 h0s[2][16][72];   // producer only
    __shared__ __align__(16) _Float16 h1s[2][16][72];   // consumer only
    __shared__ __align__(16) float h1f[16][68];         // consumer only
    __shared__ float hid[16][32];                       // consumer only

    const int tid  = threadIdx.x;
    const int w4   = tid >> 6;        // wave 0..3 = gate-column group
    const int lane = tid & 63;
    const int q  = lane >> 4;         // quad 0..3
    const int lr = lane & 15;
    const int pair = blockIdx.x >> 1;
    const bool isP = (blockIdx.x & 1) == 0;
    const int b0 = pair * 16;

    uint* wsp   = ws + (size_t)pair * PAIR_DW;
    uint* flags = wsp + FLAGS_OFF;    // flags[s] == s+1 when slot s published
    uint* prog  = wsp + PROG_OFF;     // consumer iteration counter (signed use)

    // ---- persistent weight B-fragments ----
    // Wave w4 owns gate-column tiles n = (w4+4g)*16, g in {i,f,g,o}: all four
    // gates of units [16w4,16w4+16) are lane-local at eltwise.
    // B-frag: lane holds B[k][n], n = tile+lr, k = 8q+j (W rows contiguous).
    half8 wb[4][4];
    float biasv[4];
    if (isP) {
        #pragma unroll
        for (int g = 0; g < 4; ++g) {
            int n = (w4 + 4 * g) * 16 + lr;
            wb[g][0] = load_w_frag(Wih0, n, 32, q * 8);
            wb[g][1] = load_w_frag(Whh0, n, 64, q * 8);
            wb[g][2] = load_w_frag(Whh0, n, 64, 32 + q * 8);
            biasv[g] = bih0[n] + bhh0[n];
        }
    } else {
        #pragma unroll
        for (int g = 0; g < 4; ++g) {
            int n = (w4 + 4 * g) * 16 + lr;
            wb[g][0] = load_w_frag(Wih1, n, 64, q * 8);
            wb[g][1] = load_w_frag(Wih1, n, 64, 32 + q * 8);
            wb[g][2] = load_w_frag(Whh1, n, 64, q * 8);
            wb[g][3] = load_w_frag(Whh1, n, 64, 32 + q * 8);
            biasv[g] = bih1[n] + bhh1[n];
        }
    }

    float cr[4] = {0.f, 0.f, 0.f, 0.f};

    if (isP) {
        // ================= PRODUCER: layer 0 =================
        for (int i = tid; i < 2 * 16 * 72; i += 256)
            ((_Float16*)h0s)[i] = (_Float16)0.0f;

        const int xm = tid >> 4;
        const int xf = (tid & 15) * 2;
        const float* xrow = x + ((size_t)(b0 + xm) * TT) * 32 + xf;
        float2 xbuf;
        {   // x(0) -> xs[0]; x(1) -> regs
            float2 x0 = *(const float2*)xrow;
            xs[0][xm][xf]     = (_Float16)x0.x;
            xs[0][xm][xf + 1] = (_Float16)x0.y;
            xbuf = *(const float2*)(xrow + 32);
        }

        // Iter k: publish flag(k-2); copy h0(k-1) LDS->ring; compute h0(k).
        // The barrier's implicit vmcnt(0) drain guarantees copy stores of
        // slot s are complete before flag[s]=s+1 is written next iteration.
        for (int k = 0; k <= TT + 1; ++k) {
            __syncthreads();
            if (k >= 2 && tid == 0) ws_store(&flags[k - 2], (uint)(k - 1));
            if (k >= 1 && k <= TT) {
                int s = k - 1;
                if (s >= RING) {   // ring backpressure: tenant s-16 consumed?
                    while ((int)ws_load(prog) < s - 13)
                        __builtin_amdgcn_s_sleep(8);
                }
                const uint* lsrc = (const uint*)&h0s[(k + 1) & 1][0][0];
                uint* dst = wsp + (size_t)(s & (RING - 1)) * SLOT_DW;
                int d0 = tid, d1 = tid + 256;
                uint v0 = lsrc[(d0 >> 5) * 36 + (d0 & 31)];
                uint v1 = lsrc[(d1 >> 5) * 36 + (d1 & 31)];
                ws_store(&dst[(d0 >> 5) * 32 + (d0 & 31)], v0);
                ws_store(&dst[(d1 >> 5) * 32 + (d1 & 31)], v1);
            }
            if (k < TT) {
                const int rd = (k + 1) & 1, wr = k & 1;
                half8 xfrag = *(const half8*)&xs[wr][lr][q * 8];
                half8 h0a   = *(const half8*)&h0s[rd][lr][q * 8];
                half8 h0b   = *(const half8*)&h0s[rd][lr][32 + q * 8];
                floatx4 a[4];
                #pragma unroll
                for (int g = 0; g < 4; ++g) {
                    floatx4 acc = {biasv[g], biasv[g], biasv[g], biasv[g]};
                    acc = __builtin_amdgcn_mfma_f32_16x16x32_f16(xfrag, wb[g][0], acc, 0, 0, 0);
                    acc = __builtin_amdgcn_mfma_f32_16x16x32_f16(h0a,   wb[g][1], acc, 0, 0, 0);
                    acc = __builtin_amdgcn_mfma_f32_16x16x32_f16(h0b,   wb[g][2], acc, 0, 0, 0);
                    a[g] = acc;
                }
                float hnew[4];
                #pragma unroll
                for (int r = 0; r < 4; ++r)
                    cell_update(a[0][r], a[1][r], a[2][r], a[3][r], cr[r], hnew[r]);
                #pragma unroll
                for (int r = 0; r < 4; ++r)
                    h0s[wr][q * 4 + r][w4 * 16 + lr] = (_Float16)hnew[r];
                if (k + 1 < TT) {           // stage x(k+1) -> xs[(k+1)&1]
                    xs[rd][xm][xf]     = (_Float16)xbuf.x;
                    xs[rd][xm][xf + 1] = (_Float16)xbuf.y;
                }
                if (k + 2 < TT)
                    xbuf = *(const float2*)(xrow + (size_t)(k + 2) * 32);
            }
        }
        // producer writes no output
    } else {
        // ================= CONSUMER: layer 1 =================
        for (int i = tid; i < 2 * 16 * 72; i += 256)
            ((_Float16*)h1s)[i] = (_Float16)0.0f;

        union FragBuf { uint u[8]; half8 h[2]; };
        FragBuf cur, nxt;
        #pragma unroll
        for (int i = 0; i < 8; ++i) { cur.u[i] = 0; nxt.u[i] = 0; }

        // Iter j: publish prog=j (slots <= j-3 fully consumed: their loads
        // issued iter j-1, drained by this iteration's barrier);
        // prefetch slot j-2 into nxt; compute h1(j-3) from cur; swap.
        for (int j = 0; j <= TT + 2; ++j) {
            __syncthreads();
            if (tid == 0) ws_store(prog, (uint)j);
            const int s2 = j - 2;
            if (s2 >= 0 && s2 < TT) {
                while ((int)__hip_atomic_load(&flags[s2], __ATOMIC_ACQUIRE,
                                              __HIP_MEMORY_SCOPE_AGENT) != s2 + 1)
                    __builtin_amdgcn_s_sleep(8);
                const uint* src = wsp + (size_t)(s2 & (RING - 1)) * SLOT_DW + lr * 32;
                #pragma unroll
                for (int i = 0; i < 4; ++i) nxt.u[i]     = ws_load(&src[4 * q + i]);
                #pragma unroll
                for (int i = 0; i < 4; ++i) nxt.u[4 + i] = ws_load(&src[16 + 4 * q + i]);
            }
            const int s = j - 3;
            if (s >= 0) {
                const int rd = (s + 1) & 1, wr = s & 1;
                half8 h1a = *(const half8*)&h1s[rd][lr][q * 8];
                half8 h1b = *(const half8*)&h1s[rd][lr][32 + q * 8];
                floatx4 a[4];
                #pragma unroll
                for (int g = 0; g < 4; ++g) {
                    floatx4 acc = {biasv[g], biasv[g], biasv[g], biasv[g]};
                    acc = __builtin_amdgcn_mfma_f32_16x16x32_f16(cur.h[0], wb[g][0], acc, 0, 0, 0);
                    acc = __builtin_amdgcn_mfma_f32_16x16x32_f16(cur.h[1], wb[g][1], acc, 0, 0, 0);
                    acc = __builtin_amdgcn_mfma_f32_16x16x32_f16(h1a,      wb[g][2], acc, 0, 0, 0);
                    acc = __builtin_amdgcn_mfma_f32_16x16x32_f16(h1b,      wb[g][3], acc, 0, 0, 0);
                    a[g] = acc;
                }
                float hnew[4];
                #pragma unroll
                for (int r = 0; r < 4; ++r)
                    cell_update(a[0][r], a[1][r], a[2][r], a[3][r], cr[r], hnew[r]);
                if (s == TT - 1) {
                    #pragma unroll
                    for (int r = 0; r < 4; ++r)
                        h1f[q * 4 + r][w4 * 16 + lr] = hnew[r];
                } else {
                    #pragma unroll
                    for (int r = 0; r < 4; ++r)
                        h1s[wr][q * 4 + r][w4 * 16 + lr] = (_Float16)hnew[r];
                }
            }
            cur = nxt;
        }
        __syncthreads();

        // ---- classifier (fp32): hidden = relu(hT Wc1^T + bc1); out = hidden Wc2^T + bc2
        {
            int m = tid >> 4;
            int u = (tid & 15) * 2;
            float a = bc1[u], b = bc1[u + 1];
            const float* w0 = Wc1 + u * 64;
            const float* w1 = Wc1 + (u + 1) * 64;
            #pragma unroll 8
            for (int kk = 0; kk < 64; ++kk) {
                float hv = h1f[m][kk];
                a += hv * w0[kk];
                b += hv * w1[kk];
            }
            hid[m][u]     = fmaxf(a, 0.f);
            hid[m][u + 1] = fmaxf(b, 0.f);
        }
        __syncthreads();
        if (tid < 16) {
            float o = bc2[0];
            #pragma unroll
            for (int u = 0; u < 32; ++u) o += hid[tid][u] * Wc2[u];
            out[b0 + tid] = o;
        }
    }
}

extern "C" void kernel_launch(void* const* d_in, const int* in_sizes, int n_in,
                              void* d_out, int out_size, void* d_ws, size_t ws_size,
                              hipStream_t stream) {
    (void)in_sizes; (void)n_in; (void)ws_size; (void)out_size;
    const float* x    = (const float*)d_in[0];
    const float* Wih0 = (const float*)d_in[1];
    const float* Whh0 = (const float*)d_in[2];
    const float* bih0 = (const float*)d_in[3];
    const float* bhh0 = (const float*)d_in[4];
    const float* Wih1 = (const float*)d_in[5];
    const float* Whh1 = (const float*)d_in[6];
    const float* bih1 = (const float*)d_in[7];
    const float* bhh1 = (const float*)d_in[8];
    const float* Wc1  = (const float*)d_in[9];
    const float* bc1  = (const float*)d_in[10];
    const float* Wc2  = (const float*)d_in[11];
    const float* bc2  = (const float*)d_in[12];
    lstm_pc<<<dim3(512), dim3(256), 0, stream>>>(
        x, Wih0, Whh0, bih0, bhh0, Wih1, Whh1, bih1, bhh1, Wc1, bc1, Wc2, bc2,
        (float*)d_out, (uint*)d_ws);
}

// Round 6
// 210.465 us; speedup vs baseline: 10.0256x; 10.0256x over previous
//
#include <hip/hip_runtime.h>

// LSTMClassifier: B=4096, T=128, I=32, H=64, 2-layer LSTM + MLP head.
// Round 6: r3 structure (best, 124us) + lgkm-only loop barrier + 7-trans cell.
// 256 blocks x 512 threads (8 waves): waves 0-3 layer 0 at step k, waves 4-7
// layer 1 at step k-1 (one-step skew), double-buffered LDS h-state, ONE
// barrier per timestep. The loop barrier is hand-rolled `s_waitcnt lgkmcnt(0);
// s_barrier` so in-flight global x lookahead loads are NOT drained at the
// rendezvous (compiler __syncthreads would force vmcnt(0) -- ~200-900 cyc of
// HBM latency on the critical path every step). Weights persist in per-wave
// MFMA B-fragments. f16 MFMA operands, fp32 accumulate/state.

#define TT 128
#define II 32
#define HH 64

typedef _Float16 half8 __attribute__((ext_vector_type(8)));
typedef float floatx4 __attribute__((ext_vector_type(4)));

#define LOG2E 1.4426950408889634f

// Workgroup barrier that waits only on LDS ops (lgkmcnt), not vmem.
// Safe here: all cross-wave data (h0s/h1s/xs) moves through LDS; global loads
// in flight are consumed register-side with compiler-inserted vmcnt waits.
// asm volatile + memory clobber = compiler scheduling fence (m139 precedent).
__device__ __forceinline__ void bar_lds() {
    asm volatile("s_waitcnt lgkmcnt(0)\n\ts_barrier" ::: "memory");
}

// Load 8 consecutive fp32 of row n (K-major) and convert to an f16 MFMA fragment.
__device__ __forceinline__ half8 load_w_frag(const float* __restrict__ W, int n, int K, int k0) {
    const float* p = W + (size_t)n * K + k0;
    float4 a = *(const float4*)p;
    float4 b = *(const float4*)(p + 4);
    half8 h;
    h[0] = (_Float16)a.x; h[1] = (_Float16)a.y; h[2] = (_Float16)a.z; h[3] = (_Float16)a.w;
    h[4] = (_Float16)b.x; h[5] = (_Float16)b.y; h[6] = (_Float16)b.z; h[7] = (_Float16)b.w;
    return h;
}

// LSTM cell eltwise, 7 transcendentals (5 exp + 2 rcp), HW-validated in r5:
// sig(f) and sig(i)*tanh(g) share one rcp via R = rcp(D1*D2);
// clamps at +-12 keep D1*D2 <= ~7e20 (fp32-safe) with tail error < 7e-6.
__device__ __forceinline__ void cell_update(float gi, float gf, float gg, float go,
                                            float& c, float& h) {
    gi = fminf(fmaxf(gi, -12.f), 12.f);
    gf = fminf(fmaxf(gf, -12.f), 12.f);
    gg = fminf(fmaxf(gg, -12.f), 12.f);
    float u  = __builtin_amdgcn_exp2f(gg * (2.f * LOG2E));   // e^{2g} <= 2.7e10
    float vi = __builtin_amdgcn_exp2f(-gi * LOG2E);          // <= 1.6e5
    float vf = __builtin_amdgcn_exp2f(-gf * LOG2E);          // <= 1.6e5
    float u1 = u + 1.f;
    float D1 = 1.f + vf;
    float D2 = fmaf(vi, u1, u1);                             // (1+vi)(1+u)
    float R  = __builtin_amdgcn_rcpf(D1 * D2);
    float sigf = R * D2;                                     // = 1/D1
    float sit  = (u - 1.f) * (R * D1);                       // = (u-1)/D2
    c = fmaf(sigf, c, sit);
    float cc = fminf(fmaxf(c, -12.f), 12.f);
    float w  = __builtin_amdgcn_exp2f(cc * (2.f * LOG2E));
    float vo = __builtin_amdgcn_exp2f(-go * LOG2E);
    float w1 = w + 1.f;
    float den = fmaf(vo, w1, w1);                            // (1+vo)(w+1)
    h = (w - 1.f) * __builtin_amdgcn_rcpf(den);
}

__global__ __launch_bounds__(512, 2) void lstm_fused(
    const float* __restrict__ x,
    const float* __restrict__ Wih0, const float* __restrict__ Whh0,
    const float* __restrict__ bih0, const float* __restrict__ bhh0,
    const float* __restrict__ Wih1, const float* __restrict__ Whh1,
    const float* __restrict__ bih1, const float* __restrict__ bhh1,
    const float* __restrict__ Wc1, const float* __restrict__ bc1,
    const float* __restrict__ Wc2, const float* __restrict__ bc2,
    float* __restrict__ out)
{
    // Double-buffered state; +8 f16 padding keeps 16B alignment (stride 144B)
    // with only 2-way bank aliasing on b128 reads (free per m136).
    __shared__ __align__(16) _Float16 xs[2][16][40];
    __shared__ __align__(16) _Float16 h0s[2][16][72];
    __shared__ __align__(16) _Float16 h1s[2][16][72];
    __shared__ __align__(16) float h1f[16][68];   // final-step h1 (fp32)
    __shared__ float hid[16][32];

    const int tid  = threadIdx.x;
    const int wid  = tid >> 6;        // wave 0..7
    const int w4   = wid & 3;         // gate-column group within the layer
    const bool isL0 = (wid < 4);
    const int lane = tid & 63;
    const int q  = lane >> 4;         // quad 0..3
    const int lr = lane & 15;
    const int b0 = blockIdx.x * 16;

    // ---- persistent weight fragments (registers, whole kernel) ----
    // Wave group w4 owns gate-column tiles n = (w4 + 4g)*16, g in {i,f,g,o}:
    // all four gates for channels [16*w4, 16*w4+16) are lane-local at eltwise.
    // B-frag: lane holds B[k][n], n = tile + lr, k = 8q + j; B = W^T so the
    // lane reads W[n][8q..8q+8) contiguously.
    half8 bx0[4], bh0[4][2];          // layer-0 waves
    half8 bi1[4][2], bh1[4][2];       // layer-1 waves
    float biasv[4];
    if (isL0) {
        #pragma unroll
        for (int g = 0; g < 4; ++g) {
            int n = (w4 + 4 * g) * 16 + lr;
            bx0[g]    = load_w_frag(Wih0, n, 32, q * 8);
            bh0[g][0] = load_w_frag(Whh0, n, 64, q * 8);
            bh0[g][1] = load_w_frag(Whh0, n, 64, 32 + q * 8);
            biasv[g]  = bih0[n] + bhh0[n];
        }
    } else {
        #pragma unroll
        for (int g = 0; g < 4; ++g) {
            int n = (w4 + 4 * g) * 16 + lr;
            bi1[g][0] = load_w_frag(Wih1, n, 64, q * 8);
            bi1[g][1] = load_w_frag(Wih1, n, 64, 32 + q * 8);
            bh1[g][0] = load_w_frag(Whh1, n, 64, q * 8);
            bh1[g][1] = load_w_frag(Whh1, n, 64, 32 + q * 8);
            biasv[g]  = bih1[n] + bhh1[n];
        }
    }

    // zero-init both h-state buffers (h0(-1) = h1(-1) = h1(-2) = 0)
    for (int i = tid; i < 2 * 16 * 72; i += 512) {
        ((_Float16*)h0s)[i] = (_Float16)0.0f;
        ((_Float16*)h1s)[i] = (_Float16)0.0f;
    }

    float cr[4] = {0.f, 0.f, 0.f, 0.f};   // c state for this wave's layer

    // x staging (layer-0 waves only): thread -> (row xm, 2 consecutive floats)
    const int xm = (tid >> 4) & 15;
    const int xf = (tid & 15) * 2;
    const float* xrow = x + ((size_t)(b0 + xm) * TT) * II + xf;
    float2 xbuf = {0.f, 0.f};
    if (isL0) {
        float2 x0 = *(const float2*)(xrow);            // x(0) -> xs[0]
        xs[0][xm][xf]     = (_Float16)x0.x;
        xs[0][xm][xf + 1] = (_Float16)x0.y;
        if (TT > 1) xbuf = *(const float2*)(xrow + 1 * II);  // x(1) in regs
    }

    // Iteration k: waves 0-3 compute h0(k) (k < TT); waves 4-7 compute h1(k-1)
    // (k >= 1). h*(k) -> buf[k&1]; h*(k-1) read from buf[(k+1)&1]. x(k) lives
    // in xs[k&1], staged during iter k-1. Single lgkm-only barrier per iter:
    // read- and write-buffers never alias, and writes to a buffer are
    // separated from its readers by the next barrier.
    #pragma unroll 2
    for (int k = 0; k <= TT; ++k) {
        bar_lds();

        const int rd = (k + 1) & 1;
        const int wr = k & 1;
        const bool doL0 = isL0 && (k < TT);
        const bool doL1 = (!isL0) && (k >= 1);
        float hnew[4];
        float2 xnew = xbuf;

        if (doL0) {
            // gates = bias0 + x(k) Wih0^T + h0(k-1) Whh0^T
            half8 xfrag = *(const half8*)&xs[wr][lr][q * 8];      // x(k)
            half8 h0a   = *(const half8*)&h0s[rd][lr][q * 8];
            half8 h0b   = *(const half8*)&h0s[rd][lr][32 + q * 8];
            if (k + 2 < TT) xnew = *(const float2*)(xrow + (size_t)(k + 2) * II);
            floatx4 a0[4];
            #pragma unroll
            for (int g = 0; g < 4; ++g) {
                floatx4 acc = {biasv[g], biasv[g], biasv[g], biasv[g]};
                acc = __builtin_amdgcn_mfma_f32_16x16x32_f16(xfrag, bx0[g],    acc, 0, 0, 0);
                acc = __builtin_amdgcn_mfma_f32_16x16x32_f16(h0a,   bh0[g][0], acc, 0, 0, 0);
                acc = __builtin_amdgcn_mfma_f32_16x16x32_f16(h0b,   bh0[g][1], acc, 0, 0, 0);
                a0[g] = acc;
            }
            #pragma unroll
            for (int r = 0; r < 4; ++r)
                cell_update(a0[0][r], a0[1][r], a0[2][r], a0[3][r], cr[r], hnew[r]);
        }
        if (doL1) {
            // gates = bias1 + h0(k-1) Wih1^T + h1(k-2) Whh1^T
            half8 g0a = *(const half8*)&h0s[rd][lr][q * 8];
            half8 g0b = *(const half8*)&h0s[rd][lr][32 + q * 8];
            half8 h1a = *(const half8*)&h1s[rd][lr][q * 8];
            half8 h1b = *(const half8*)&h1s[rd][lr][32 + q * 8];
            floatx4 a1[4];
            #pragma unroll
            for (int g = 0; g < 4; ++g) {
                floatx4 acc = {biasv[g], biasv[g], biasv[g], biasv[g]};
                acc = __builtin_amdgcn_mfma_f32_16x16x32_f16(g0a, bi1[g][0], acc, 0, 0, 0);
                acc = __builtin_amdgcn_mfma_f32_16x16x32_f16(g0b, bi1[g][1], acc, 0, 0, 0);
                acc = __builtin_amdgcn_mfma_f32_16x16x32_f16(h1a, bh1[g][0], acc, 0, 0, 0);
                acc = __builtin_amdgcn_mfma_f32_16x16x32_f16(h1b, bh1[g][1], acc, 0, 0, 0);
                a1[g] = acc;
            }
            #pragma unroll
            for (int r = 0; r < 4; ++r)
                cell_update(a1[0][r], a1[1][r], a1[2][r], a1[3][r], cr[r], hnew[r]);
        }

        // writes go to buf[wr]; readers of buf[wr] are past the next barrier
        if (doL0) {
            #pragma unroll
            for (int r = 0; r < 4; ++r)
                h0s[wr][q * 4 + r][w4 * 16 + lr] = (_Float16)hnew[r];
            if (k + 1 < TT) {                       // stage x(k+1) -> xs[(k+1)&1]
                xs[rd][xm][xf]     = (_Float16)xbuf.x;
                xs[rd][xm][xf + 1] = (_Float16)xbuf.y;
            }
            xbuf = xnew;
        }
        if (doL1) {
            if (k == TT) {
                #pragma unroll
                for (int r = 0; r < 4; ++r)
                    h1f[q * 4 + r][w4 * 16 + lr] = hnew[r];
            } else {
                #pragma unroll
                for (int r = 0; r < 4; ++r)
                    h1s[wr][q * 4 + r][w4 * 16 + lr] = (_Float16)hnew[r];
            }
        }
    }
    __syncthreads();   // full drain once, outside the hot loop

    // ---- classifier (fp32): hidden = relu(hT Wc1^T + bc1); out = hidden Wc2^T + bc2
    if (tid < 256) {
        int m = tid >> 4;
        int u = (tid & 15) * 2;
        float a = bc1[u], b = bc1[u + 1];
        const float* w0 = Wc1 + u * 64;
        const float* w1 = Wc1 + (u + 1) * 64;
        #pragma unroll 8
        for (int kk = 0; kk < 64; ++kk) {
            float hv = h1f[m][kk];
            a += hv * w0[kk];
            b += hv * w1[kk];
        }
        hid[m][u]     = fmaxf(a, 0.f);
        hid[m][u + 1] = fmaxf(b, 0.f);
    }
    __syncthreads();
    if (tid < 16) {
        float o = bc2[0];
        #pragma unroll
        for (int u = 0; u < 32; ++u) o += hid[tid][u] * Wc2[u];
        out[b0 + tid] = o;
    }
}

extern "C" void kernel_launch(void* const* d_in, const int* in_sizes, int n_in,
                              void* d_out, int out_size, void* d_ws, size_t ws_size,
                              hipStream_t stream) {
    (void)in_sizes; (void)n_in; (void)d_ws; (void)ws_size; (void)out_size;
    const float* x    = (const float*)d_in[0];
    const float* Wih0 = (const float*)d_in[1];
    const float* Whh0 = (const float*)d_in[2];
    const float* bih0 = (const float*)d_in[3];
    const float* bhh0 = (const float*)d_in[4];
    const float* Wih1 = (const float*)d_in[5];
    const float* Whh1 = (const float*)d_in[6];
    const float* bih1 = (const float*)d_in[7];
    const float* bhh1 = (const float*)d_in[8];
    const float* Wc1  = (const float*)d_in[9];
    const float* bc1  = (const float*)d_in[10];
    const float* Wc2  = (const float*)d_in[11];
    const float* bc2  = (const float*)d_in[12];
    lstm_fused<<<dim3(256), dim3(512), 0, stream>>>(
        x, Wih0, Whh0, bih0, bhh0, Wih1, Whh1, bih1, bhh1, Wc1, bc1, Wc2, bc2,
        (float*)d_out);
}